// Round 9
// baseline (321.699 us; speedup 1.0000x reference)
//
#include <hip/hip_runtime.h>
#include <hip/hip_bf16.h>
#include <stdint.h>

#define B_ 8
#define K_ 2048
#define D_ 1024
#define NC 32
#define TC (K_ / NC)   // 64 timesteps per chunk

typedef float v4f __attribute__((ext_vector_type(4)));
typedef short v8s __attribute__((ext_vector_type(8)));

__device__ __forceinline__ unsigned short f2bf(float f) {
    __hip_bfloat16 h = __float2bfloat16(f);
    return *reinterpret_cast<unsigned short*>(&h);
}

__device__ __forceinline__ void async_ld16(const void* g, void* l) {
    __builtin_amdgcn_global_load_lds(
        (__attribute__((address_space(1))) void*)(void*)g,
        (__attribute__((address_space(3))) void*)l,
        16, 0, 0);
}

// ------- fused converters: blocks [0,4096) = W->bf16; [4096,8192) = x->xT -------
__global__ void conv_all(const float* __restrict__ W, unsigned short* __restrict__ Wb,
                         const float* __restrict__ x, unsigned short* __restrict__ xT) {
    if (blockIdx.x < 4096) {
        int i = (blockIdx.x * 256 + threadIdx.x) * 4;
        float4 v = *(const float4*)(W + i);
        ushort4 o;
        o.x = f2bf(v.x); o.y = f2bf(v.y); o.z = f2bf(v.z); o.w = f2bf(v.w);
        *(ushort4*)(Wb + i) = o;
        return;
    }
    const int t = blockIdx.x - 4096;
    const int k0 = (t & 31) * 64, d0 = ((t >> 5) & 15) * 64, bb = t >> 9;
    __shared__ unsigned short tile[64][68];   // pad 68 to break bank alignment
    const int tid = threadIdx.x;
    const int tx = tid & 15, ty = tid >> 4;
    const float* xp = x + (size_t)bb * K_ * D_;
#pragma unroll
    for (int r = 0; r < 4; r++) {
        int row = ty + r * 16;
        float4 v = *(const float4*)(xp + (size_t)(k0 + row) * D_ + d0 + tx * 4);
        tile[row][tx * 4 + 0] = f2bf(v.x);
        tile[row][tx * 4 + 1] = f2bf(v.y);
        tile[row][tx * 4 + 2] = f2bf(v.z);
        tile[row][tx * 4 + 3] = f2bf(v.w);
    }
    __syncthreads();
    unsigned short* op = xT + (size_t)bb * D_ * K_;
#pragma unroll
    for (int r = 0; r < 4; r++) {
        int dcol = ty + r * 16;
        ushort4 u;
        u.x = tile[tx * 4 + 0][dcol];
        u.y = tile[tx * 4 + 1][dcol];
        u.z = tile[tx * 4 + 2][dcol];
        u.w = tile[tx * 4 + 3][dcol];
        *(ushort4*)(op + (size_t)(d0 + dcol) * K_ + k0 + tx * 4) = u;
    }
}

// ---------------- GEMM + bias + sigmoid (+ fused chunk-scan pass1) ----------------
// R9: back to the proven 256x256 / 8-wave / 1-WG/CU geometry (R4, 85 us), with
// ONE structural change targeting the measured bottleneck (per-half ds-drain
// ~1150 cyc serialized against MFMA ~1241 by lgkmcnt(0)):
//   A (=W) BYPASSES LDS. The A-frag is 8 k-contiguous bf16 at a per-lane global
//   address -> loaded b128 straight from Wb (L2-served: the 4 tN-WGs per XCD
//   share each A-panel). Ping-pong register prefetch one half ahead; the
//   COMPILER's auto-vmcnt waits the exact count before first MFMA use.
//   B keeps the LDS ring (2 x 16 KiB, BK=32) staged via global_load_lds.
// Per half: 1 barrier; lgkmcnt(0) covers only 4 B-frag ds_reads (~380 cyc/CU,
// fits under MFMA). vmcnt ordering: STAGE_B issued BEFORE the A-loads, so
// vmcnt(8) at half-end drains the 2 gload_lds while the 8 A-prefetch loads stay
// in flight; sched_barrier(0) pins the issue order (loads must not sink past
// the counted waitcnt).
// VGPR ~235 (acc 128 + af/afn 64 + bf 16 + addr) < 256 @ 2 waves/SIMD.
__launch_bounds__(512, 2)
__global__ void gemm_sig(const unsigned short* __restrict__ Wb,
                         const unsigned short* __restrict__ xT,
                         const float* __restrict__ bias,
                         const float* __restrict__ xf,
                         float* __restrict__ lam,
                         float* __restrict__ Ac,
                         float* __restrict__ Uc,
                         int fuse) {
    // B ring: [2][256*32] hw = 32 KiB; rest of the 128 KiB is epilogue scratch.
    __shared__ __align__(16) unsigned char lds_raw[131072];
    unsigned short* Bs = (unsigned short*)lds_raw;

    // XCD-chunked bijective swizzle (nwg=256): one batch b per XCD -> xT[b] ~ L2;
    // the 4 tN-WGs per (XCD, tM) share one A-panel -> A reads are L2 hits.
    const int bid = blockIdx.x;
    const int lid = (bid & 7) * 32 + (bid >> 3);
    const int bb = lid >> 5;          // batch
    const int tM = (lid >> 2) & 7;    // 8 M-tiles
    const int tN = lid & 3;           // 4 N-tiles

    const int tid = threadIdx.x;
    const int w = tid >> 6;           // wave 0..7
    const int lane = tid & 63;
    const int wm = w >> 2;            // 0..1  (M)
    const int wn = w & 3;             // 0..3  (N)
    const int quad = lane >> 4;
    const int l16 = lane & 15;

    const unsigned short* Bg = xT + (size_t)bb * D_ * K_ + (size_t)(tN * 256) * K_;
    // per-lane A base: row = tM*256 + wm*128 + i*16 + l16, k-chunk quad*8
    const unsigned short* Agl = Wb + (size_t)(tM * 256 + wm * 128 + l16) * K_ + quad * 8;

    // B staging constants (source XOR matches read XOR — rule #21; 0 conflicts)
    const int srow = lane >> 2;
    const int sgk8 = ((lane & 3) ^ ((lane >> 3) & 3)) * 8;
    const int frg = (quad ^ ((l16 >> 1) & 3)) * 8;
    const int b_hw = (wn * 64 + l16) * 32 + frg;

    v4f acc[8][4];
#pragma unroll
    for (int i = 0; i < 8; i++)
#pragma unroll
        for (int j = 0; j < 4; j++) acc[i][j] = (v4f)0.f;

#define STAGE_B_(hh)                                                                        \
    do {                                                                                    \
        const int buf_ = ((hh) & 1) * 8192; const int ko_ = (hh) * 32;                      \
        async_ld16(Bg + (size_t)(w * 16 + srow) * K_ + ko_ + sgk8, Bs + buf_ + w * 512);    \
        async_ld16(Bg + (size_t)((8 + w) * 16 + srow) * K_ + ko_ + sgk8,                    \
                   Bs + buf_ + (8 + w) * 512);                                              \
    } while (0)

#define LOADA_(dst, hh)                                                                     \
    do {                                                                                    \
        _Pragma("unroll")                                                                   \
        for (int i = 0; i < 8; i++)                                                         \
            dst[i] = *(const v8s*)(Agl + (size_t)i * 16 * K_ + (hh) * 32);                  \
    } while (0)

    v8s afA[8], afB[8], bf[4];

    // prologue: stage B(0) (vm+2), prefetch A(0) (vm+8); vmcnt(8) drains stage.
    STAGE_B_(0);
    __builtin_amdgcn_sched_barrier(0);
    LOADA_(afA, 0);
    __builtin_amdgcn_sched_barrier(0);
    asm volatile("s_waitcnt vmcnt(8)");
    asm volatile("s_barrier" ::: "memory");

    // one half per barrier; USE = regs for half hh, PRE = prefetch target (hh+1)
#define HALF_(hh, USE, PRE, DO_PRE, DO_STG)                                                 \
    do {                                                                                    \
        const unsigned short* Bc_ = Bs + ((hh) & 1) * 8192;                                 \
        _Pragma("unroll")                                                                   \
        for (int j = 0; j < 4; j++) bf[j] = *(const v8s*)(&Bc_[b_hw + j * 512]);            \
        if (DO_STG) STAGE_B_((hh) + 1);                                                     \
        __builtin_amdgcn_sched_barrier(0);                                                  \
        if (DO_PRE) LOADA_(PRE, (hh) + 1);                                                  \
        __builtin_amdgcn_sched_barrier(0);                                                  \
        asm volatile("s_barrier" ::: "memory");                                             \
        asm volatile("s_waitcnt lgkmcnt(0)");                                               \
        __builtin_amdgcn_sched_barrier(0);                                                  \
        __builtin_amdgcn_s_setprio(1);                                                      \
        _Pragma("unroll")                                                                   \
        for (int i = 0; i < 8; i++)                                                         \
            _Pragma("unroll")                                                               \
            for (int j = 0; j < 4; j++)                                                     \
                acc[i][j] = __builtin_amdgcn_mfma_f32_16x16x32_bf16(USE[i], bf[j], acc[i][j], 0, 0, 0); \
        __builtin_amdgcn_s_setprio(0);                                                      \
        asm volatile("s_waitcnt vmcnt(8)");                                                 \
        asm volatile("s_barrier" ::: "memory");                                             \
    } while (0)

    const int H = K_ / 32;            // 64 halves
    for (int h = 0; h < H - 2; h += 2) {
        HALF_(h, afA, afB, 1, 1);
        HALF_(h + 1, afB, afA, 1, 1);
    }
    HALF_(H - 2, afA, afB, 1, 1);     // stages B(63), prefetches A(63)
    HALF_(H - 1, afB, afA, 0, 0);     // nothing new in flight
#undef HALF_
#undef STAGE_B_
#undef LOADA_

    // after the final barrier all waves are done with the B ring -> scratch safe
    float* out = lam + (size_t)bb * K_ * D_;
    const int dg = tN * 256 + wn * 64;       // wave col base in d

    if (fuse) {
        // wave-private 64x64 f32 scratch (16 KiB each, 8 waves = 128 KiB)
        float* Swp = (float*)lds_raw + w * 4096;
        const int swzw = quad * 16;          // write-side XOR: ((R>>2)&3)*16 == quad*16
#pragma unroll
        for (int cg = 0; cg < 2; cg++) {
            const int c = tM * 4 + wm * 2 + cg;   // global chunk id
            const int t0 = c * 64;
#pragma unroll
            for (int ii = 0; ii < 4; ii++) {
                int i = cg * 4 + ii;
                int rowb = t0 + ii * 16 + quad * 4;   // global t row base
                int Rb = ii * 16 + quad * 4;          // row within chunk
#pragma unroll
                for (int r = 0; r < 4; r++) {
                    float bt = bias[rowb + r];
#pragma unroll
                    for (int j = 0; j < 4; j++) {
                        int colc = j * 16 + l16;
                        float v = acc[i][j][r] + bt;
                        float sg = 1.f / (1.f + __expf(-v));
                        out[(size_t)(rowb + r) * D_ + dg + colc] = sg;
                        Swp[(Rb + r) * 64 + (colc ^ swzw)] = sg;
                    }
                }
            }
            asm volatile("s_waitcnt lgkmcnt(0)");
            __builtin_amdgcn_sched_barrier(0);
            // sequential chunk scan: lane owns column d = dg + lane; streaming x
            // reads (8 in flight via unroll) — proven form, no register blow-up.
            const float* xg = xf + ((size_t)bb * K_ + t0) * D_ + dg + lane;
            float A = 1.f, U = 0.f;
#pragma unroll 8
            for (int tt = 0; tt < 64; tt++) {
                float l = Swp[tt * 64 + (lane ^ (((tt >> 2) & 3) * 16))];
                float xv = xg[(size_t)tt * D_];
                A *= l;
                U = l * U + (1.f - l) * xv;
            }
            size_t oi = ((size_t)bb * NC + c) * D_ + dg + lane;
            Ac[oi] = A;
            Uc[oi] = U;
            __builtin_amdgcn_sched_barrier(0);   // keep cg=1 writes below cg=0 reads
        }
    } else {
        // plain epilogue (fallback when ws too small for fused Ac/Uc placement)
#pragma unroll
        for (int i = 0; i < 8; i++) {
            int rowb = tM * 256 + wm * 128 + i * 16 + quad * 4;
#pragma unroll
            for (int r = 0; r < 4; r++) {
                float bt = bias[rowb + r];
#pragma unroll
                for (int j = 0; j < 4; j++) {
                    int col = tN * 256 + wn * 64 + j * 16 + l16;
                    float v = acc[i][j][r] + bt;
                    out[(size_t)(rowb + r) * D_ + col] = 1.f / (1.f + __expf(-v));
                }
            }
        }
    }
}

// -------- scan pass 1 (FALLBACK ONLY): per-(b,chunk,d2) affine composition --------
__global__ void scan_pass1(const float* __restrict__ lam, const float* __restrict__ x,
                           float* __restrict__ Ac, float* __restrict__ Uc) {
    int id = blockIdx.x * 256 + threadIdx.x;   // B*NC*D/2 = 131072
    int d2 = (id & 511) * 2;
    int c = (id >> 9) & (NC - 1);
    int bb = id >> 14;
    const float* lp = lam + ((size_t)bb * K_ + (size_t)c * TC) * D_ + d2;
    const float* xp = x   + ((size_t)bb * K_ + (size_t)c * TC) * D_ + d2;
    float2 A = make_float2(1.f, 1.f), U = make_float2(0.f, 0.f);
#pragma unroll 8
    for (int t = 0; t < TC; t++) {
        float2 l  = *(const float2*)(lp + (size_t)t * D_);
        float2 xv = *(const float2*)(xp + (size_t)t * D_);
        A.x *= l.x; A.y *= l.y;
        U.x = l.x * U.x + (1.f - l.x) * xv.x;
        U.y = l.y * U.y + (1.f - l.y) * xv.y;
    }
    size_t oi = ((size_t)bb * NC + c) * D_ + d2;
    *(float2*)(Ac + oi) = A;
    *(float2*)(Uc + oi) = U;
}

// -------- scan pass 3 (absorbs pass 2): prefix over chunks + replay --------
// float2/lane, 512 blocks x 256 thr = 2 blocks/CU = 8 waves/CU; nontemporal
// stores keep L2 for the lam/x read streams. (Best-total config, R5.)
__launch_bounds__(256)
__global__ void scan_pass3(const float* __restrict__ x,
                           const float* __restrict__ Ac, const float* __restrict__ Uc,
                           float* __restrict__ lamout) {
    int id = blockIdx.x * 256 + threadIdx.x;   // B*NC*D/2 = 131072
    int d = (id & 511) * 2;
    int c = (id >> 9) & (NC - 1);
    int bb = id >> 14;
    float2 s = make_float2(0.f, 0.f);
    for (int j = 0; j < c; j++) {
        size_t ji = ((size_t)bb * NC + j) * D_ + d;
        float2 A = *(const float2*)(Ac + ji);
        float2 U = *(const float2*)(Uc + ji);
        s.x = A.x * s.x + U.x;
        s.y = A.y * s.y + U.y;
    }
    float* lp = lamout + ((size_t)bb * K_ + (size_t)c * TC) * D_ + d;
    const float* xp = x + ((size_t)bb * K_ + (size_t)c * TC) * D_ + d;
#pragma unroll 8
    for (int t = 0; t < TC; t++) {
        float2 l  = *(const float2*)(lp + (size_t)t * D_);
        float2 xv = *(const float2*)(xp + (size_t)t * D_);
        s.x = l.x * s.x + (1.f - l.x) * xv.x;
        s.y = l.y * s.y + (1.f - l.y) * xv.y;
        __builtin_nontemporal_store(s.x, lp + (size_t)t * D_);
        __builtin_nontemporal_store(s.y, lp + (size_t)t * D_ + 1);
    }
}

extern "C" void kernel_launch(void* const* d_in, const int* in_sizes, int n_in,
                              void* d_out, int out_size, void* d_ws, size_t ws_size,
                              hipStream_t stream) {
    const float* x    = (const float*)d_in[0];
    const float* W    = (const float*)d_in[1];
    const float* bias = (const float*)d_in[2];
    float* out = (float*)d_out;
    char* ws = (char*)d_ws;

    unsigned short* xT = (unsigned short*)ws;                       // 32 MiB  [B][D][K] bf16
    unsigned short* Wb = (unsigned short*)(ws + 33554432);          // 8 MiB   [K][K] bf16

    // Fused path needs Ac/Uc live DURING gemm (other WGs still read Wb/xT), so
    // they must sit in fresh ws after Wb: needs 40 MiB + 2 MiB = 44040192 B.
    const int fuse = (ws_size >= 44040192u) ? 1 : 0;
    float* Ac, * Uc;
    if (fuse) {
        Ac = (float*)(ws + 41943040);
        Uc = (float*)(ws + 41943040 + 1048576);
    } else {
        Ac = (float*)(ws + 33554432);                // overlay Wb (dead post-gemm)
        Uc = (float*)(ws + 33554432 + 1048576);
    }

    conv_all<<<dim3(8192), 256, 0, stream>>>(W, Wb, x, xT);
    // lam goes into d_out; pass3 overwrites it in place with the final scan output
    gemm_sig<<<dim3(256), dim3(512), 0, stream>>>(Wb, xT, bias, x, out, Ac, Uc, fuse);
    if (!fuse)
        scan_pass1<<<dim3(B_ * NC * D_ / 2 / 256), 256, 0, stream>>>(out, x, Ac, Uc);
    scan_pass3<<<dim3(B_ * NC * D_ / 2 / 256), 256, 0, stream>>>(x, Ac, Uc, out);
}

// Round 10
// 236.777 us; speedup vs baseline: 1.3587x; 1.3587x over previous
//
#include <hip/hip_runtime.h>
#include <hip/hip_bf16.h>
#include <stdint.h>

#define B_ 8
#define K_ 2048
#define D_ 1024
#define NC 32
#define TC (K_ / NC)   // 64 timesteps per chunk

typedef float v4f __attribute__((ext_vector_type(4)));
typedef short v8s __attribute__((ext_vector_type(8)));

__device__ __forceinline__ unsigned short f2bf(float f) {
    __hip_bfloat16 h = __float2bfloat16(f);
    return *reinterpret_cast<unsigned short*>(&h);
}

__device__ __forceinline__ void async_ld16(const void* g, void* l) {
    __builtin_amdgcn_global_load_lds(
        (__attribute__((address_space(1))) void*)(void*)g,
        (__attribute__((address_space(3))) void*)l,
        16, 0, 0);
}

// ------- fused converters: blocks [0,4096) = W->bf16; [4096,8192) = x->xT -------
__global__ void conv_all(const float* __restrict__ W, unsigned short* __restrict__ Wb,
                         const float* __restrict__ x, unsigned short* __restrict__ xT) {
    if (blockIdx.x < 4096) {
        int i = (blockIdx.x * 256 + threadIdx.x) * 4;
        float4 v = *(const float4*)(W + i);
        ushort4 o;
        o.x = f2bf(v.x); o.y = f2bf(v.y); o.z = f2bf(v.z); o.w = f2bf(v.w);
        *(ushort4*)(Wb + i) = o;
        return;
    }
    const int t = blockIdx.x - 4096;
    const int k0 = (t & 31) * 64, d0 = ((t >> 5) & 15) * 64, bb = t >> 9;
    __shared__ unsigned short tile[64][68];   // pad 68 to break bank alignment
    const int tid = threadIdx.x;
    const int tx = tid & 15, ty = tid >> 4;
    const float* xp = x + (size_t)bb * K_ * D_;
#pragma unroll
    for (int r = 0; r < 4; r++) {
        int row = ty + r * 16;
        float4 v = *(const float4*)(xp + (size_t)(k0 + row) * D_ + d0 + tx * 4);
        tile[row][tx * 4 + 0] = f2bf(v.x);
        tile[row][tx * 4 + 1] = f2bf(v.y);
        tile[row][tx * 4 + 2] = f2bf(v.z);
        tile[row][tx * 4 + 3] = f2bf(v.w);
    }
    __syncthreads();
    unsigned short* op = xT + (size_t)bb * D_ * K_;
#pragma unroll
    for (int r = 0; r < 4; r++) {
        int dcol = ty + r * 16;
        ushort4 u;
        u.x = tile[tx * 4 + 0][dcol];
        u.y = tile[tx * 4 + 1][dcol];
        u.z = tile[tx * 4 + 2][dcol];
        u.w = tile[tx * 4 + 3][dcol];
        *(ushort4*)(op + (size_t)(d0 + dcol) * K_ + k0 + tx * 4) = u;
    }
}

// ---------------- GEMM + bias + sigmoid (+ fused chunk-scan pass1) ----------------
// R10 = R4 VERBATIM (measured 84.4-85.7 us, VGPR 120, 0 bank conflicts): 256x256
// tile, 8 waves (2M x 4N), 4-phase K-loop, counted vmcnt(4), XOR-swizzled LDS,
// last K-iteration peeled, epilogue streaming-x scan unroll 8.
// Five restructures (R5 unroll16, R6 4-deep ring, R7 A-reg-prefetch, R8 2WG/CU,
// R9 A-from-global) all measured WORSE (87-174 us). This structure is the
// plateau; do not perturb without a mechanism that removes the barrier-resync
// cost (~21 us over the serialized read+MFMA floor).
__launch_bounds__(512, 2)
__global__ void gemm_sig(const unsigned short* __restrict__ Wb,
                         const unsigned short* __restrict__ xT,
                         const float* __restrict__ bias,
                         const float* __restrict__ xf,
                         float* __restrict__ lam,
                         float* __restrict__ Ac,
                         float* __restrict__ Uc,
                         int fuse) {
    // [op][buf][kh][256 rows * 32 hw] : op0=A(W), op1=B(xT). 128 KiB total.
    __shared__ __align__(16) unsigned short smem_all[2][2][2][256 * 32];

    // XCD-chunked bijective swizzle (nwg=256): one batch b per XCD -> xT[b] ~ L2.
    const int bid = blockIdx.x;
    const int lid = (bid & 7) * 32 + (bid >> 3);
    const int bb = lid >> 5;          // batch
    const int tM = (lid >> 2) & 7;    // 8 M-tiles
    const int tN = lid & 3;           // 4 N-tiles

    const int tid = threadIdx.x;
    const int w = tid >> 6;           // wave 0..7
    const int lane = tid & 63;
    const int wm = w >> 2;            // 0..1  (M)
    const int wn = w & 3;             // 0..3  (N)
    const int quad = lane >> 4;
    const int l16 = lane & 15;

    const unsigned short* Ag = Wb + (size_t)(tM * 256) * K_;
    const unsigned short* Bg = xT + (size_t)bb * D_ * K_ + (size_t)(tN * 256) * K_;

    // staging lane constants: 1KB LDS block = 16 rows x 4 granules (16B each);
    // lane l holds granule gk = (l&3) ^ ((l>>3)&3) so LDS slot matches the
    // ds_read-side XOR (rule #21: gload_lds dest stays lane-linear; swizzle the
    // global source + the read address with the same involution).
    const int srow = lane >> 2;
    const int sgk8 = ((lane & 3) ^ ((lane >> 3) & 3)) * 8;   // halfword offset

    const int frg = (quad ^ ((l16 >> 1) & 3)) * 8;
    const int aoff = (wm * 128 + l16) * 32 + frg;
    const int boff = (wn * 64 + l16) * 32 + frg;

    v4f acc[8][4];
#pragma unroll
    for (int i = 0; i < 8; i++)
#pragma unroll
        for (int j = 0; j < 4; j++) acc[i][j] = (v4f)0.f;

#define STAGE_(op, bufi, kh, kk, Gp)                                                        \
    do {                                                                                    \
        async_ld16(Gp + (size_t)(w * 16 + srow) * K_ + (kk) + (kh) * 32 + sgk8,             \
                   &smem_all[op][bufi][kh][w * 512]);                                       \
        async_ld16(Gp + (size_t)((8 + w) * 16 + srow) * K_ + (kk) + (kh) * 32 + sgk8,       \
                   &smem_all[op][bufi][kh][(8 + w) * 512]);                                 \
    } while (0)

    // prologue: tile 0's 4 halves
    STAGE_(0, 0, 0, 0, Ag);
    STAGE_(1, 0, 0, 0, Bg);
    STAGE_(0, 0, 1, 0, Ag);
    STAGE_(1, 0, 1, 0, Bg);
    asm volatile("s_waitcnt vmcnt(4)");
    asm volatile("s_barrier" ::: "memory");

    v8s af[8], bf[2];

    const int NT = K_ / 64;           // 32
    for (int t = 0; t < NT - 1; ++t) {
        const int cur = t & 1, nxt = cur ^ 1;
        const int k1 = (t + 1) * 64;  // never wraps (t <= NT-2)

        // ---------------- phase 1: kh0, j01 ----------------
#pragma unroll
        for (int i = 0; i < 8; i++) af[i] = *(const v8s*)(&smem_all[0][cur][0][aoff + i * 512]);
        bf[0] = *(const v8s*)(&smem_all[1][cur][0][boff]);
        bf[1] = *(const v8s*)(&smem_all[1][cur][0][boff + 512]);
        STAGE_(0, nxt, 0, k1, Ag);
        asm volatile("s_barrier" ::: "memory");
        asm volatile("s_waitcnt lgkmcnt(0)");
        __builtin_amdgcn_sched_barrier(0);
        __builtin_amdgcn_s_setprio(1);
#pragma unroll
        for (int i = 0; i < 8; i++) {
            acc[i][0] = __builtin_amdgcn_mfma_f32_16x16x32_bf16(af[i], bf[0], acc[i][0], 0, 0, 0);
            acc[i][1] = __builtin_amdgcn_mfma_f32_16x16x32_bf16(af[i], bf[1], acc[i][1], 0, 0, 0);
        }
        __builtin_amdgcn_s_setprio(0);
        asm volatile("s_barrier" ::: "memory");

        // ---------------- phase 2: kh0, j23 ----------------
        bf[0] = *(const v8s*)(&smem_all[1][cur][0][boff + 2 * 512]);
        bf[1] = *(const v8s*)(&smem_all[1][cur][0][boff + 3 * 512]);
        STAGE_(1, nxt, 0, k1, Bg);
        asm volatile("s_barrier" ::: "memory");
        asm volatile("s_waitcnt lgkmcnt(0)");
        __builtin_amdgcn_sched_barrier(0);
        __builtin_amdgcn_s_setprio(1);
#pragma unroll
        for (int i = 0; i < 8; i++) {
            acc[i][2] = __builtin_amdgcn_mfma_f32_16x16x32_bf16(af[i], bf[0], acc[i][2], 0, 0, 0);
            acc[i][3] = __builtin_amdgcn_mfma_f32_16x16x32_bf16(af[i], bf[1], acc[i][3], 0, 0, 0);
        }
        __builtin_amdgcn_s_setprio(0);
        asm volatile("s_waitcnt vmcnt(4)");   // tile-t kh1 halves now resident
        asm volatile("s_barrier" ::: "memory");

        // ---------------- phase 3: kh1, j01 ----------------
#pragma unroll
        for (int i = 0; i < 8; i++) af[i] = *(const v8s*)(&smem_all[0][cur][1][aoff + i * 512]);
        bf[0] = *(const v8s*)(&smem_all[1][cur][1][boff]);
        bf[1] = *(const v8s*)(&smem_all[1][cur][1][boff + 512]);
        STAGE_(0, nxt, 1, k1, Ag);
        asm volatile("s_barrier" ::: "memory");
        asm volatile("s_waitcnt lgkmcnt(0)");
        __builtin_amdgcn_sched_barrier(0);
        __builtin_amdgcn_s_setprio(1);
#pragma unroll
        for (int i = 0; i < 8; i++) {
            acc[i][0] = __builtin_amdgcn_mfma_f32_16x16x32_bf16(af[i], bf[0], acc[i][0], 0, 0, 0);
            acc[i][1] = __builtin_amdgcn_mfma_f32_16x16x32_bf16(af[i], bf[1], acc[i][1], 0, 0, 0);
        }
        __builtin_amdgcn_s_setprio(0);
        asm volatile("s_barrier" ::: "memory");

        // ---------------- phase 4: kh1, j23 ----------------
        bf[0] = *(const v8s*)(&smem_all[1][cur][1][boff + 2 * 512]);
        bf[1] = *(const v8s*)(&smem_all[1][cur][1][boff + 3 * 512]);
        STAGE_(1, nxt, 1, k1, Bg);
        asm volatile("s_barrier" ::: "memory");
        asm volatile("s_waitcnt lgkmcnt(0)");
        __builtin_amdgcn_sched_barrier(0);
        __builtin_amdgcn_s_setprio(1);
#pragma unroll
        for (int i = 0; i < 8; i++) {
            acc[i][2] = __builtin_amdgcn_mfma_f32_16x16x32_bf16(af[i], bf[0], acc[i][2], 0, 0, 0);
            acc[i][3] = __builtin_amdgcn_mfma_f32_16x16x32_bf16(af[i], bf[1], acc[i][3], 0, 0, 0);
        }
        __builtin_amdgcn_s_setprio(0);
        asm volatile("s_waitcnt vmcnt(4)");   // tile-(t+1) kh0 halves now resident
        asm volatile("s_barrier" ::: "memory");
    }

    // ---------------- peeled last iteration (t = NT-1): no staging ----------------
    {
        const int cur = (NT - 1) & 1;
        // phase 1: kh0, j01
#pragma unroll
        for (int i = 0; i < 8; i++) af[i] = *(const v8s*)(&smem_all[0][cur][0][aoff + i * 512]);
        bf[0] = *(const v8s*)(&smem_all[1][cur][0][boff]);
        bf[1] = *(const v8s*)(&smem_all[1][cur][0][boff + 512]);
        asm volatile("s_barrier" ::: "memory");
        asm volatile("s_waitcnt lgkmcnt(0)");
        __builtin_amdgcn_sched_barrier(0);
        __builtin_amdgcn_s_setprio(1);
#pragma unroll
        for (int i = 0; i < 8; i++) {
            acc[i][0] = __builtin_amdgcn_mfma_f32_16x16x32_bf16(af[i], bf[0], acc[i][0], 0, 0, 0);
            acc[i][1] = __builtin_amdgcn_mfma_f32_16x16x32_bf16(af[i], bf[1], acc[i][1], 0, 0, 0);
        }
        __builtin_amdgcn_s_setprio(0);
        asm volatile("s_barrier" ::: "memory");

        // phase 2: kh0, j23
        bf[0] = *(const v8s*)(&smem_all[1][cur][0][boff + 2 * 512]);
        bf[1] = *(const v8s*)(&smem_all[1][cur][0][boff + 3 * 512]);
        asm volatile("s_barrier" ::: "memory");
        asm volatile("s_waitcnt lgkmcnt(0)");
        __builtin_amdgcn_sched_barrier(0);
        __builtin_amdgcn_s_setprio(1);
#pragma unroll
        for (int i = 0; i < 8; i++) {
            acc[i][2] = __builtin_amdgcn_mfma_f32_16x16x32_bf16(af[i], bf[0], acc[i][2], 0, 0, 0);
            acc[i][3] = __builtin_amdgcn_mfma_f32_16x16x32_bf16(af[i], bf[1], acc[i][3], 0, 0, 0);
        }
        __builtin_amdgcn_s_setprio(0);
        asm volatile("s_waitcnt vmcnt(0)");   // kh1 halves resident (nothing else in flight)
        asm volatile("s_barrier" ::: "memory");

        // phase 3: kh1, j01
#pragma unroll
        for (int i = 0; i < 8; i++) af[i] = *(const v8s*)(&smem_all[0][cur][1][aoff + i * 512]);
        bf[0] = *(const v8s*)(&smem_all[1][cur][1][boff]);
        bf[1] = *(const v8s*)(&smem_all[1][cur][1][boff + 512]);
        asm volatile("s_waitcnt lgkmcnt(0)");
        __builtin_amdgcn_sched_barrier(0);
        __builtin_amdgcn_s_setprio(1);
#pragma unroll
        for (int i = 0; i < 8; i++) {
            acc[i][0] = __builtin_amdgcn_mfma_f32_16x16x32_bf16(af[i], bf[0], acc[i][0], 0, 0, 0);
            acc[i][1] = __builtin_amdgcn_mfma_f32_16x16x32_bf16(af[i], bf[1], acc[i][1], 0, 0, 0);
        }
        __builtin_amdgcn_s_setprio(0);

        // phase 4: kh1, j23
        bf[0] = *(const v8s*)(&smem_all[1][cur][1][boff + 2 * 512]);
        bf[1] = *(const v8s*)(&smem_all[1][cur][1][boff + 3 * 512]);
        asm volatile("s_waitcnt lgkmcnt(0)");
        __builtin_amdgcn_sched_barrier(0);
        __builtin_amdgcn_s_setprio(1);
#pragma unroll
        for (int i = 0; i < 8; i++) {
            acc[i][2] = __builtin_amdgcn_mfma_f32_16x16x32_bf16(af[i], bf[0], acc[i][2], 0, 0, 0);
            acc[i][3] = __builtin_amdgcn_mfma_f32_16x16x32_bf16(af[i], bf[1], acc[i][3], 0, 0, 0);
        }
        __builtin_amdgcn_s_setprio(0);
        asm volatile("s_barrier" ::: "memory");   // all waves done with LDS -> scratch reuse safe
    }
#undef STAGE_

    float* out = lam + (size_t)bb * K_ * D_;
    const int dg = tN * 256 + wn * 64;       // wave col base in d

    if (fuse) {
        // wave-private 64x64 f32 scratch (16 KiB each, 8 waves = 128 KiB = all LDS)
        float* Swp = (float*)smem_all + w * 4096;
        const int swzw = quad * 16;          // write-side XOR: ((R>>2)&3)*16 == quad*16
#pragma unroll
        for (int cg = 0; cg < 2; cg++) {
            const int c = tM * 4 + wm * 2 + cg;   // global chunk id
            const int t0 = c * 64;
#pragma unroll
            for (int ii = 0; ii < 4; ii++) {
                int i = cg * 4 + ii;
                int rowb = t0 + ii * 16 + quad * 4;   // global t row base
                int Rb = ii * 16 + quad * 4;          // row within chunk
#pragma unroll
                for (int r = 0; r < 4; r++) {
                    float bt = bias[rowb + r];
#pragma unroll
                    for (int j = 0; j < 4; j++) {
                        int colc = j * 16 + l16;
                        float v = acc[i][j][r] + bt;
                        float sg = 1.f / (1.f + __expf(-v));
                        out[(size_t)(rowb + r) * D_ + dg + colc] = sg;
                        Swp[(Rb + r) * 64 + (colc ^ swzw)] = sg;
                    }
                }
            }
            asm volatile("s_waitcnt lgkmcnt(0)");
            __builtin_amdgcn_sched_barrier(0);
            // sequential chunk scan: lane owns column d = dg + lane; streaming x
            // reads (8 in flight via unroll) — proven form, no register blow-up.
            const float* xg = xf + ((size_t)bb * K_ + t0) * D_ + dg + lane;
            float A = 1.f, U = 0.f;
#pragma unroll 8
            for (int tt = 0; tt < 64; tt++) {
                float l = Swp[tt * 64 + (lane ^ (((tt >> 2) & 3) * 16))];
                float xv = xg[(size_t)tt * D_];
                A *= l;
                U = l * U + (1.f - l) * xv;
            }
            size_t oi = ((size_t)bb * NC + c) * D_ + dg + lane;
            Ac[oi] = A;
            Uc[oi] = U;
            __builtin_amdgcn_sched_barrier(0);   // keep cg=1 writes below cg=0 reads
        }
    } else {
        // plain epilogue (fallback when ws too small for fused Ac/Uc placement)
#pragma unroll
        for (int i = 0; i < 8; i++) {
            int rowb = tM * 256 + wm * 128 + i * 16 + quad * 4;
#pragma unroll
            for (int r = 0; r < 4; r++) {
                float bt = bias[rowb + r];
#pragma unroll
                for (int j = 0; j < 4; j++) {
                    int col = tN * 256 + wn * 64 + j * 16 + l16;
                    float v = acc[i][j][r] + bt;
                    out[(size_t)(rowb + r) * D_ + col] = 1.f / (1.f + __expf(-v));
                }
            }
        }
    }
}

// -------- scan pass 1 (FALLBACK ONLY): per-(b,chunk,d2) affine composition --------
__global__ void scan_pass1(const float* __restrict__ lam, const float* __restrict__ x,
                           float* __restrict__ Ac, float* __restrict__ Uc) {
    int id = blockIdx.x * 256 + threadIdx.x;   // B*NC*D/2 = 131072
    int d2 = (id & 511) * 2;
    int c = (id >> 9) & (NC - 1);
    int bb = id >> 14;
    const float* lp = lam + ((size_t)bb * K_ + (size_t)c * TC) * D_ + d2;
    const float* xp = x   + ((size_t)bb * K_ + (size_t)c * TC) * D_ + d2;
    float2 A = make_float2(1.f, 1.f), U = make_float2(0.f, 0.f);
#pragma unroll 8
    for (int t = 0; t < TC; t++) {
        float2 l  = *(const float2*)(lp + (size_t)t * D_);
        float2 xv = *(const float2*)(xp + (size_t)t * D_);
        A.x *= l.x; A.y *= l.y;
        U.x = l.x * U.x + (1.f - l.x) * xv.x;
        U.y = l.y * U.y + (1.f - l.y) * xv.y;
    }
    size_t oi = ((size_t)bb * NC + c) * D_ + d2;
    *(float2*)(Ac + oi) = A;
    *(float2*)(Uc + oi) = U;
}

// -------- scan pass 3 (absorbs pass 2): prefix over chunks + replay --------
// float2/lane, 512 blocks x 256 thr = 2 blocks/CU = 8 waves/CU; nontemporal
// stores keep L2 for the lam/x read streams. (R5 form — best measured tail.)
__launch_bounds__(256)
__global__ void scan_pass3(const float* __restrict__ x,
                           const float* __restrict__ Ac, const float* __restrict__ Uc,
                           float* __restrict__ lamout) {
    int id = blockIdx.x * 256 + threadIdx.x;   // B*NC*D/2 = 131072
    int d = (id & 511) * 2;
    int c = (id >> 9) & (NC - 1);
    int bb = id >> 14;
    float2 s = make_float2(0.f, 0.f);
    for (int j = 0; j < c; j++) {
        size_t ji = ((size_t)bb * NC + j) * D_ + d;
        float2 A = *(const float2*)(Ac + ji);
        float2 U = *(const float2*)(Uc + ji);
        s.x = A.x * s.x + U.x;
        s.y = A.y * s.y + U.y;
    }
    float* lp = lamout + ((size_t)bb * K_ + (size_t)c * TC) * D_ + d;
    const float* xp = x + ((size_t)bb * K_ + (size_t)c * TC) * D_ + d;
#pragma unroll 8
    for (int t = 0; t < TC; t++) {
        float2 l  = *(const float2*)(lp + (size_t)t * D_);
        float2 xv = *(const float2*)(xp + (size_t)t * D_);
        s.x = l.x * s.x + (1.f - l.x) * xv.x;
        s.y = l.y * s.y + (1.f - l.y) * xv.y;
        __builtin_nontemporal_store(s.x, lp + (size_t)t * D_);
        __builtin_nontemporal_store(s.y, lp + (size_t)t * D_ + 1);
    }
}

extern "C" void kernel_launch(void* const* d_in, const int* in_sizes, int n_in,
                              void* d_out, int out_size, void* d_ws, size_t ws_size,
                              hipStream_t stream) {
    const float* x    = (const float*)d_in[0];
    const float* W    = (const float*)d_in[1];
    const float* bias = (const float*)d_in[2];
    float* out = (float*)d_out;
    char* ws = (char*)d_ws;

    unsigned short* xT = (unsigned short*)ws;                       // 32 MiB  [B][D][K] bf16
    unsigned short* Wb = (unsigned short*)(ws + 33554432);          // 8 MiB   [K][K] bf16

    // Fused path needs Ac/Uc live DURING gemm (other WGs still read Wb/xT), so
    // they must sit in fresh ws after Wb: needs 40 MiB + 2 MiB = 44040192 B.
    const int fuse = (ws_size >= 44040192u) ? 1 : 0;
    float* Ac, * Uc;
    if (fuse) {
        Ac = (float*)(ws + 41943040);
        Uc = (float*)(ws + 41943040 + 1048576);
    } else {
        Ac = (float*)(ws + 33554432);                // overlay Wb (dead post-gemm)
        Uc = (float*)(ws + 33554432 + 1048576);
    }

    conv_all<<<dim3(8192), 256, 0, stream>>>(W, Wb, x, xT);
    // lam goes into d_out; pass3 overwrites it in place with the final scan output
    gemm_sig<<<dim3(256), dim3(512), 0, stream>>>(Wb, xT, bias, x, out, Ac, Uc, fuse);
    if (!fuse)
        scan_pass1<<<dim3(B_ * NC * D_ / 2 / 256), 256, 0, stream>>>(out, x, Ac, Uc);
    scan_pass3<<<dim3(B_ * NC * D_ / 2 / 256), 256, 0, stream>>>(x, Ac, Uc, out);
}